// Round 15
// baseline (126.346 us; speedup 1.0000x reference)
//
#include <hip/hip_runtime.h>
#include <hip/hip_bf16.h>
#include <hip/hip_cooperative_groups.h>

#define NROWS 262144
#define NBF 256            // blocks (1 per CU, cooperative co-resident)
#define RPBF 1024          // rows per block
#define NCH 16             // chunks of 64 rows
// exp(x*0.125) == exp2(x * 0.125*log2(e))
#define CL 0.18033688011112042f
#define PW 20              // padded panel width (ushorts)

typedef __attribute__((ext_vector_type(8))) short s8v;   // 8 bf16 (4 VGPRs)
typedef __attribute__((ext_vector_type(4))) short s4h;   // 4 bf16 (2 VGPRs)
typedef __attribute__((ext_vector_type(4))) float f4v;   // float4 / MFMA acc

__device__ __forceinline__ short f2bf(float x) {         // RNE float->bf16 bits
    unsigned u = __float_as_uint(x);
    u += 0x7FFF + ((u >> 16) & 1);
    return (short)(u >> 16);
}

// sum over each contiguous 16-lane group via DPP (VALU pipe only)
__device__ __forceinline__ float dpp_red16(float x) {
    int t;
    t = __builtin_amdgcn_update_dpp(0, __float_as_int(x), 0xB1,  0xF, 0xF, true); // quad xor1
    x += __int_as_float(t);
    t = __builtin_amdgcn_update_dpp(0, __float_as_int(x), 0x4E,  0xF, 0xF, true); // quad xor2
    x += __int_as_float(t);
    t = __builtin_amdgcn_update_dpp(0, __float_as_int(x), 0x141, 0xF, 0xF, true); // half_mirror
    x += __int_as_float(t);
    t = __builtin_amdgcn_update_dpp(0, __float_as_int(x), 0x140, 0xF, 0xF, true); // mirror
    x += __int_as_float(t);
    return x;
}

// asm load: compiler cannot sink/split/shrink these
#define GL4(dst, base, OFF) \
    asm volatile("global_load_dwordx4 %0, %1, off offset:" #OFF \
                 : "=v"(dst) : "v"(base))

// Fused kernel: phase1 = R12's pipelined kk^T@V + colsum partials + q~ into
// LDS; grid.sync; phase2 = ctx'/colsum reduce (64 blocks); grid.sync;
// phase3 = out = q~ @ ctx' from LDS q~. Q,K,V each read exactly once.
__global__ __launch_bounds__(512, 2) void kfused(const float* __restrict__ Q,
                                                 const float* __restrict__ K,
                                                 const float* __restrict__ V,
                                                 float* __restrict__ ctx_part,  // [NBF][4096]
                                                 float* __restrict__ qs_part,   // [NBF][64]
                                                 ushort* __restrict__ ctxfT,    // [64][64] bf16
                                                 float* __restrict__ out)
{
    const int tid  = threadIdx.x;
    const int lane = tid & 63;
    const int wid  = tid >> 6;          // 8 waves
    const int m    = lane & 15;         // col-quad (cols 4m..4m+3)
    const int g    = lane >> 4;         // row-in-quad
    const int cb   = wid >> 1;          // wave's c-tile
    const int vb0  = (wid & 1) * 2;     // wave's v-tiles vb0, vb0+1
    const size_t base = (size_t)blockIdx.x * RPBF;

    __shared__ ushort kkP[4][64][PW];       // 10 KB  [panel][chunk row][col]
    __shared__ ushort vP [4][64][PW];       // 10 KB
    __shared__ ushort qtL[RPBF * 64];       // 128 KB q~ bf16, XOR-swizzled rows
    __shared__ float  qsl[8][64];           // 2 KB

    // ---------------- phase 1 ----------------
    f4v acc0 = {0.f, 0.f, 0.f, 0.f};
    f4v acc1 = {0.f, 0.f, 0.f, 0.f};
    f4v qs4  = {0.f, 0.f, 0.f, 0.f};
    f4v kf[2][2], vf[2][2], qf[2][2];   // 2-deep ring: 6 loads/chunk (48 VGPRs)

#define ISSUE(CH, PB) do { \
        const float* kb = K + (base + (CH) * 64 + wid * 8 + g) * 64 + 4 * m; \
        const float* vb = V + (base + (CH) * 64 + wid * 8 + g) * 64 + 4 * m; \
        const float* qb = Q + (base + (CH) * 64 + wid * 8 + g) * 64 + 4 * m; \
        GL4(kf[PB][0], kb, 0); GL4(kf[PB][1], kb, 1024); \
        GL4(vf[PB][0], vb, 0); GL4(vf[PB][1], vb, 1024); \
        GL4(qf[PB][0], qb, 0); GL4(qf[PB][1], qb, 1024); \
    } while (0)

    ISSUE(0, 0);

#pragma unroll
    for (int ch = 0; ch < NCH; ++ch) {
        const int pb = ch & 1;
        if (ch < NCH - 1) {
            switch (ch + 1) {
                case 1:  ISSUE(1, 1);  break; case 2:  ISSUE(2, 0);  break;
                case 3:  ISSUE(3, 1);  break; case 4:  ISSUE(4, 0);  break;
                case 5:  ISSUE(5, 1);  break; case 6:  ISSUE(6, 0);  break;
                case 7:  ISSUE(7, 1);  break; case 8:  ISSUE(8, 0);  break;
                case 9:  ISSUE(9, 1);  break; case 10: ISSUE(10, 0); break;
                case 11: ISSUE(11, 1); break; case 12: ISSUE(12, 0); break;
                case 13: ISSUE(13, 1); break; case 14: ISSUE(14, 0); break;
                case 15: ISSUE(15, 1); break;
            }
            asm volatile("s_waitcnt vmcnt(6)" ::: "memory");   // current chunk done
        } else {
            asm volatile("s_waitcnt vmcnt(0)" ::: "memory");
        }
        __builtin_amdgcn_sched_barrier(0);

        // Q: exp2 once -> colsum partials + q~ into swizzled LDS
#pragma unroll
        for (int i = 0; i < 2; ++i) {
            const float e0 = exp2f(qf[pb][i][0] * CL), e1 = exp2f(qf[pb][i][1] * CL);
            const float e2 = exp2f(qf[pb][i][2] * CL), e3 = exp2f(qf[pb][i][3] * CL);
            qs4[0] += e0; qs4[1] += e1; qs4[2] += e2; qs4[3] += e3;
            const int lq = ch * 64 + wid * 8 + 4 * i + g;      // local q~ row
            const unsigned off = (unsigned)lq * 128u +
                                 ((unsigned)(8 * m) ^ (((unsigned)lq & 7u) << 4));
            *(s4h*)((char*)qtL + off) = s4h{f2bf(e0), f2bf(e1), f2bf(e2), f2bf(e3)};
        }
        // K row softmax (args bounded, no max): row = 16-lane group
        f4v e4[2]; float rs[2];
#pragma unroll
        for (int i = 0; i < 2; ++i) {
            e4[i][0] = exp2f(kf[pb][i][0] * CL); e4[i][1] = exp2f(kf[pb][i][1] * CL);
            e4[i][2] = exp2f(kf[pb][i][2] * CL); e4[i][3] = exp2f(kf[pb][i][3] * CL);
            rs[i] = dpp_red16((e4[i][0] + e4[i][1]) + (e4[i][2] + e4[i][3]));
        }
        s4h kp[2], vp4[2];
#pragma unroll
        for (int i = 0; i < 2; ++i) {
            const float inv = __builtin_amdgcn_rcpf(rs[i]);
            kp[i]  = s4h{f2bf(e4[i][0] * inv), f2bf(e4[i][1] * inv),
                         f2bf(e4[i][2] * inv), f2bf(e4[i][3] * inv)};
            vp4[i] = s4h{f2bf(vf[pb][i][0]), f2bf(vf[pb][i][1]),
                         f2bf(vf[pb][i][2]), f2bf(vf[pb][i][3])};
        }

        __syncthreads();                 // prev chunk's frag reads done
#pragma unroll
        for (int i = 0; i < 2; ++i) {
            const int lr = wid * 8 + 4 * i + g;       // chunk-local row
            *(s4h*)&kkP[m >> 2][lr][(m & 3) * 4] = kp[i];
            *(s4h*)&vP [m >> 2][lr][(m & 3) * 4] = vp4[i];
        }
        __syncthreads();

        // fragments via plain u16 column reads; wave's 2 tiles (cb, vb0/+1)
#pragma unroll
        for (int ks = 0; ks < 2; ++ks) {
            s8v bf, af0, af1;
#pragma unroll
            for (int e = 0; e < 8; ++e) {
                bf[e]  = (short)kkP[cb][32 * ks + 8 * g + e][m];
                af0[e] = (short)vP[vb0][32 * ks + 8 * g + e][m];
                af1[e] = (short)vP[vb0 + 1][32 * ks + 8 * g + e][m];
            }
            acc0 = __builtin_amdgcn_mfma_f32_16x16x32_bf16(af0, bf, acc0, 0, 0, 0);
            acc1 = __builtin_amdgcn_mfma_f32_16x16x32_bf16(af1, bf, acc1, 0, 0, 0);
        }
    }
#undef ISSUE

    // wave-disjoint tile writes (no cross-wave reduce)
    *(f4v*)&ctx_part[(size_t)blockIdx.x * 4096 +
                     (cb * 16 + m) * 64 + vb0 * 16 + 4 * g]       = acc0;
    *(f4v*)&ctx_part[(size_t)blockIdx.x * 4096 +
                     (cb * 16 + m) * 64 + (vb0 + 1) * 16 + 4 * g] = acc1;

#pragma unroll
    for (int c = 0; c < 4; ++c) {
        qs4[c] += __shfl_xor(qs4[c], 16);
        qs4[c] += __shfl_xor(qs4[c], 32);
    }
    if (g == 0) *(f4v*)&qsl[wid][4 * m] = qs4;
    __syncthreads();
    if (tid < 64) {
        float s = 0.f;
#pragma unroll
        for (int w = 0; w < 8; ++w) s += qsl[w][tid];
        qs_part[blockIdx.x * 64 + tid] = s;
    }

    cooperative_groups::this_grid().sync();

    // ---------------- phase 2 (blocks 0..63) ----------------
    if (blockIdx.x < 64) {
        const int c = blockIdx.x;
        float* redf = (float*)&kkP[0][0][0];       // 1024 floats scratch
        float* qred = redf + 1024;                 // 256 floats scratch
        if (tid < 256) {
            const int bg = tid >> 4, vq = tid & 15;
            f4v s = {0.f, 0.f, 0.f, 0.f};
            for (int b = bg; b < NBF; b += 16)
                s += *(const f4v*)&ctx_part[(size_t)b * 4096 + c * 64 + vq * 4];
            *(f4v*)&redf[(bg * 16 + vq) * 4] = s;
            qred[tid] = qs_part[tid * 64 + c];
        }
        __syncthreads();
        if (tid < 64) {
            float t = 0.f;
#pragma unroll
            for (int b = 0; b < 16; ++b) t += redf[(b * 16 + (tid >> 2)) * 4 + (tid & 3)];
            float qv = (qred[tid] + qred[tid + 64]) + (qred[tid + 128] + qred[tid + 192]);
            qv = dpp_red16(qv);
            qv += __shfl_xor(qv, 16);
            qv += __shfl_xor(qv, 32);
            ctxfT[tid * 64 + c] = (ushort)f2bf(t * __builtin_amdgcn_rcpf(qv));
        }
    }

    cooperative_groups::this_grid().sync();

    // ---------------- phase 3: out = q~ @ ctx' (q~ from LDS) ----------------
    const int li = lane & 15;
    s8v ct[4][2];                       // A frags: ctxfT[va*16+li][32ks+8g..+7]
#pragma unroll
    for (int va = 0; va < 4; ++va)
#pragma unroll
        for (int ks = 0; ks < 2; ++ks)
            ct[va][ks] = *(const s8v*)((const char*)ctxfT +
                            2 * ((va * 16 + li) * 64 + 32 * ks + 8 * g));

#pragma unroll
    for (int it = 0; it < 8; ++it) {
        const int lrow = it * 128 + wid * 16 + li;      // local row
        const unsigned swz = ((unsigned)lrow & 7u) << 4;
        const unsigned rb  = (unsigned)lrow * 128u;
        const s8v b0 = *(const s8v*)((const char*)qtL + rb + ((unsigned)(16 * g) ^ swz));
        const s8v b1 = *(const s8v*)((const char*)qtL + rb + ((unsigned)(64 + 16 * g) ^ swz));
#pragma unroll
        for (int va = 0; va < 4; ++va) {
            f4v a = {0.f, 0.f, 0.f, 0.f};
            a = __builtin_amdgcn_mfma_f32_16x16x32_bf16(ct[va][0], b0, a, 0, 0, 0);
            a = __builtin_amdgcn_mfma_f32_16x16x32_bf16(ct[va][1], b1, a, 0, 0, 0);
            *(f4v*)&out[(base + (size_t)lrow) * 64 + va * 16 + 4 * g] = a;
        }
    }
}

extern "C" void kernel_launch(void* const* d_in, const int* in_sizes, int n_in,
                              void* d_out, int out_size, void* d_ws, size_t ws_size,
                              hipStream_t stream) {
    const float* Q = (const float*)d_in[0];
    const float* K = (const float*)d_in[1];
    const float* V = (const float*)d_in[2];
    float* out = (float*)d_out;

    float* w = (float*)d_ws;
    size_t off = 0;
    float*  qs_part = w + off;              off += (size_t)NBF * 64;   // 64 KB
    ushort* ctxfT   = (ushort*)(w + off);   off += 2048;               // 8 KB
    float* ctx_part;
    const size_t need = (off + (size_t)NBF * 4096) * sizeof(float);    // +4 MB
    if (ws_size >= need) {
        ctx_part = w + off;
    } else {
        // partials live in d_out scratch (phase 2 consumes them before
        // phase 3 overwrites all of out)
        ctx_part = out;
    }

    void* args[] = {(void*)&Q, (void*)&K, (void*)&V,
                    (void*)&ctx_part, (void*)&qs_part, (void*)&ctxfT, (void*)&out};
    hipLaunchCooperativeKernel((void*)kfused, dim3(NBF), dim3(512), args, 0, stream);
}

// Round 16
// 74.315 us; speedup vs baseline: 1.7001x; 1.7001x over previous
//
#include <hip/hip_runtime.h>
#include <hip/hip_bf16.h>

#define NROWS 262144
#define NB1 512            // k1 blocks
#define RPB 512            // rows per k1 block (8 chunks of 64)
// exp(x*0.125) == exp2(x * 0.125*log2(e))
#define CL 0.18033688011112042f
#define PW 20              // padded panel width (ushorts)

typedef __attribute__((ext_vector_type(8))) short s8v;   // 8 bf16 (4 VGPRs)
typedef __attribute__((ext_vector_type(4))) short s4h;   // 4 bf16 (2 VGPRs)
typedef __attribute__((ext_vector_type(4))) float f4v;   // float4 / MFMA acc

__device__ __forceinline__ short f2bf(float x) {         // RNE float->bf16 bits
    unsigned u = __float_as_uint(x);
    u += 0x7FFF + ((u >> 16) & 1);
    return (short)(u >> 16);
}

// sum over each contiguous 16-lane group via DPP (VALU pipe only)
__device__ __forceinline__ float dpp_red16(float x) {
    int t;
    t = __builtin_amdgcn_update_dpp(0, __float_as_int(x), 0xB1,  0xF, 0xF, true); // quad xor1
    x += __int_as_float(t);
    t = __builtin_amdgcn_update_dpp(0, __float_as_int(x), 0x4E,  0xF, 0xF, true); // quad xor2
    x += __int_as_float(t);
    t = __builtin_amdgcn_update_dpp(0, __float_as_int(x), 0x141, 0xF, 0xF, true); // half_mirror
    x += __int_as_float(t);
    t = __builtin_amdgcn_update_dpp(0, __float_as_int(x), 0x140, 0xF, 0xF, true); // mirror
    x += __int_as_float(t);
    return x;
}

// asm load: compiler cannot sink/split/shrink these
#define GL4(dst, base, OFF) \
    asm volatile("global_load_dwordx4 %0, %1, off offset:" #OFF \
                 : "=v"(dst) : "v"(base))

// K1 (R12, best measured): 4 waves x 16 rows/chunk, 8 chunks, 2-deep
// asm-pinned register prefetch ring with counted vmcnt, PW-padded LDS
// panels, u16 frag reads, 8 MFMAs/chunk. Q colsums fused.
__global__ __launch_bounds__(256, 2) void k1_stats(const float* __restrict__ Q,
                                                   const float* __restrict__ K,
                                                   const float* __restrict__ V,
                                                   float* __restrict__ ctx_part,  // [NB1][c][v]
                                                   float* __restrict__ qs_part)   // [NB1][64]
{
    const int tid  = threadIdx.x;
    const int lane = tid & 63;
    const int wid  = tid >> 6;          // 4 waves
    const int m    = lane & 15;         // col-quad (cols 4m..4m+3)
    const int g    = lane >> 4;         // row-in-quad
    const size_t base = (size_t)blockIdx.x * RPB;

    __shared__ ushort kkP[4][64][PW];   // [panel][chunk row][col] (padded)
    __shared__ ushort vP [4][64][PW];
    __shared__ float  qsl[4][64];

    f4v acc[4];
#pragma unroll
    for (int va = 0; va < 4; ++va) acc[va] = f4v{0.f, 0.f, 0.f, 0.f};
    f4v qs4 = {0.f, 0.f, 0.f, 0.f};

    f4v kf[2][4], vf[2][4], qf[2][4];   // 2-deep prefetch ring (96 VGPRs)

#define ISSUE(CH, PB) do { \
        const float* kb = K + (base + (CH) * 64 + wid * 16 + g) * 64 + 4 * m; \
        const float* vb = V + (base + (CH) * 64 + wid * 16 + g) * 64 + 4 * m; \
        const float* qb = Q + (base + (CH) * 64 + wid * 16 + g) * 64 + 4 * m; \
        GL4(kf[PB][0], kb, 0); GL4(kf[PB][1], kb, 1024); \
        GL4(kf[PB][2], kb, 2048); GL4(kf[PB][3], kb, 3072); \
        GL4(vf[PB][0], vb, 0); GL4(vf[PB][1], vb, 1024); \
        GL4(vf[PB][2], vb, 2048); GL4(vf[PB][3], vb, 3072); \
        GL4(qf[PB][0], qb, 0); GL4(qf[PB][1], qb, 1024); \
        GL4(qf[PB][2], qb, 2048); GL4(qf[PB][3], qb, 3072); \
    } while (0)

    ISSUE(0, 0);

#pragma unroll
    for (int ch = 0; ch < 8; ++ch) {
        const int pb = ch & 1;
        if (ch < 7) {
            switch (ch + 1) {           // compile-time CH for the macro (unrolled)
                case 1: ISSUE(1, 1); break; case 2: ISSUE(2, 0); break;
                case 3: ISSUE(3, 1); break; case 4: ISSUE(4, 0); break;
                case 5: ISSUE(5, 1); break; case 6: ISSUE(6, 0); break;
                case 7: ISSUE(7, 1); break;
            }
            asm volatile("s_waitcnt vmcnt(12)" ::: "memory");  // current 12 done
        } else {
            asm volatile("s_waitcnt vmcnt(0)" ::: "memory");
        }
        __builtin_amdgcn_sched_barrier(0);

        // Q colsum partials (col 4m+c fixed per lane)
#pragma unroll
        for (int i = 0; i < 4; ++i) {
            qs4[0] += exp2f(qf[pb][i][0] * CL); qs4[1] += exp2f(qf[pb][i][1] * CL);
            qs4[2] += exp2f(qf[pb][i][2] * CL); qs4[3] += exp2f(qf[pb][i][3] * CL);
        }
        // K row softmax (args bounded, no max): row = 16-lane group
        f4v e4[4]; float rs[4];
#pragma unroll
        for (int i = 0; i < 4; ++i) {
            e4[i][0] = exp2f(kf[pb][i][0] * CL); e4[i][1] = exp2f(kf[pb][i][1] * CL);
            e4[i][2] = exp2f(kf[pb][i][2] * CL); e4[i][3] = exp2f(kf[pb][i][3] * CL);
        }
#pragma unroll
        for (int i = 0; i < 4; ++i)
            rs[i] = dpp_red16((e4[i][0] + e4[i][1]) + (e4[i][2] + e4[i][3]));
        s4h kp[4], vp4[4];
#pragma unroll
        for (int i = 0; i < 4; ++i) {
            const float inv = __builtin_amdgcn_rcpf(rs[i]);
            kp[i]  = s4h{f2bf(e4[i][0] * inv), f2bf(e4[i][1] * inv),
                         f2bf(e4[i][2] * inv), f2bf(e4[i][3] * inv)};
            vp4[i] = s4h{f2bf(vf[pb][i][0]), f2bf(vf[pb][i][1]),
                         f2bf(vf[pb][i][2]), f2bf(vf[pb][i][3])};
        }

        __syncthreads();                 // prev chunk's frag reads done
#pragma unroll
        for (int i = 0; i < 4; ++i) {
            const int lr = wid * 16 + i * 4 + g;      // chunk-local row
            *(s4h*)&kkP[m >> 2][lr][(m & 3) * 4] = kp[i];
            *(s4h*)&vP [m >> 2][lr][(m & 3) * 4] = vp4[i];
        }
        __syncthreads();

        // fragments via plain u16 column reads (row 32ks+8g+e, col m)
#pragma unroll
        for (int ks = 0; ks < 2; ++ks) {
            s8v bf;
#pragma unroll
            for (int e = 0; e < 8; ++e)
                bf[e] = (short)kkP[wid][32 * ks + 8 * g + e][m];
            s8v af[4];
#pragma unroll
            for (int va = 0; va < 4; ++va)
#pragma unroll
                for (int e = 0; e < 8; ++e)
                    af[va][e] = (short)vP[va][32 * ks + 8 * g + e][m];
#pragma unroll
            for (int va = 0; va < 4; ++va)
                acc[va] = __builtin_amdgcn_mfma_f32_16x16x32_bf16(af[va], bf, acc[va], 0, 0, 0);
        }
    }
#undef ISSUE

    // D[c][v]: c = wid*16 + m, v = va*16 + 4g + r (consecutive -> dwordx4)
#pragma unroll
    for (int va = 0; va < 4; ++va)
        *(f4v*)&ctx_part[(size_t)blockIdx.x * 4096 +
                         (wid * 16 + m) * 64 + va * 16 + 4 * g] = acc[va];

    // Q colsum: combine the 4 row-groups sharing col-quad m
#pragma unroll
    for (int c = 0; c < 4; ++c) {
        qs4[c] += __shfl_xor(qs4[c], 16);
        qs4[c] += __shfl_xor(qs4[c], 32);
    }
    if (g == 0) *(f4v*)&qsl[wid][4 * m] = qs4;
    __syncthreads();
    if (tid < 64)
        qs_part[blockIdx.x * 64 + tid] =
            (qsl[0][tid] + qsl[1][tid]) + (qsl[2][tid] + qsl[3][tid]);
}

// K2: one block per column c. float4 reduce of ctx partials + Q colsum
// partials; fold 1/colsum; emit ctx' TRANSPOSED bf16: ctxfT[v][c].
__global__ __launch_bounds__(256) void k2(const float* __restrict__ ctx_part,
                                          const float* __restrict__ qs_part,
                                          ushort* __restrict__ ctxfT) {
    const int c = blockIdx.x;        // 64 blocks
    const int tid = threadIdx.x;
    const int bg = tid >> 4, vq = tid & 15;
    __shared__ f4v  red[16][16];
    __shared__ float qred[4][64];
    f4v s = {0.f, 0.f, 0.f, 0.f};
    for (int b = bg; b < NB1; b += 16)
        s += *(const f4v*)&ctx_part[(size_t)b * 4096 + c * 64 + vq * 4];
    float q = 0.f;
    for (int b = tid; b < NB1; b += 256) q += qs_part[b * 64 + c];
    red[bg][vq] = s;
    qred[tid >> 6][tid & 63] = q;
    __syncthreads();
    if (tid < 64) {
        float t = 0.f;
#pragma unroll
        for (int b = 0; b < 16; ++b) t += red[b][tid >> 2][tid & 3];
        float qv = (qred[0][tid] + qred[1][tid]) + (qred[2][tid] + qred[3][tid]);
        qv = dpp_red16(qv);
        qv += __shfl_xor(qv, 16);
        qv += __shfl_xor(qv, 32);
        ctxfT[tid * 64 + c] = (ushort)f2bf(t * __builtin_amdgcn_rcpf(qv));
    }
}

// K3: out = q~ @ ctx' via MFMA with swapped operands (A=ctx'^T frags, B=q~
// frags) so D frags give 4 consecutive out cols/lane -> dwordx4 stores.
__global__ __launch_bounds__(256) void k3_out(const float* __restrict__ Q,
                                              const ushort* __restrict__ ctxfT,
                                              float* __restrict__ out) {
    const int tid  = threadIdx.x;
    const int lane = tid & 63;
    const int wid  = tid >> 6;      // 4 waves
    const int li = lane & 15, g = lane >> 4;

    s8v ct[4][2];                   // A frags: ctxfT[va*16+li][32ks+8g .. +7]
#pragma unroll
    for (int va = 0; va < 4; ++va)
#pragma unroll
        for (int ks = 0; ks < 2; ++ks)
            ct[va][ks] = *(const s8v*)((const char*)ctxfT +
                            2 * ((va * 16 + li) * 64 + 32 * ks + 8 * g));

#pragma unroll
    for (int t = 0; t < 4; ++t) {
        const int row = blockIdx.x * 256 + t * 64 + wid * 16 + li;
        const f4v* qp = (const f4v*)(Q + (size_t)row * 64);
        f4v q0 = qp[2 * g], q1 = qp[2 * g + 1];          // cols 8g..+7   (ks=0)
        f4v q2 = qp[8 + 2 * g], q3 = qp[8 + 2 * g + 1];  // cols 32+8g..+7 (ks=1)
        s8v b0, b1;                 // B frags: q~[row][32ks+8g .. +7]
#pragma unroll
        for (int e = 0; e < 4; ++e) {
            b0[e]     = f2bf(exp2f(q0[e] * CL));
            b0[e + 4] = f2bf(exp2f(q1[e] * CL));
            b1[e]     = f2bf(exp2f(q2[e] * CL));
            b1[e + 4] = f2bf(exp2f(q3[e] * CL));
        }
#pragma unroll
        for (int va = 0; va < 4; ++va) {
            f4v a = {0.f, 0.f, 0.f, 0.f};
            a = __builtin_amdgcn_mfma_f32_16x16x32_bf16(ct[va][0], b0, a, 0, 0, 0);
            a = __builtin_amdgcn_mfma_f32_16x16x32_bf16(ct[va][1], b1, a, 0, 0, 0);
            *(f4v*)&out[(size_t)row * 64 + va * 16 + 4 * g] = a;   // 4 consecutive v
        }
    }
}

extern "C" void kernel_launch(void* const* d_in, const int* in_sizes, int n_in,
                              void* d_out, int out_size, void* d_ws, size_t ws_size,
                              hipStream_t stream) {
    const float* Q = (const float*)d_in[0];
    const float* K = (const float*)d_in[1];
    const float* V = (const float*)d_in[2];
    float* out = (float*)d_out;

    float* w = (float*)d_ws;
    size_t off = 0;
    float*  qs_part = w + off;              off += (size_t)NB1 * 64;   // 128 KB
    ushort* ctxfT   = (ushort*)(w + off);   off += 2048;               // 8 KB
    float* ctx_part;
    const size_t need = (off + (size_t)NB1 * 4096) * sizeof(float);
    if (ws_size >= need) {
        ctx_part = w + off;
    } else {
        // 8.4 MB of partials live in d_out scratch (k3 fully overwrites later)
        ctx_part = out;
    }

    k1_stats<<<NB1, 256, 0, stream>>>(Q, K, V, ctx_part, qs_part);
    k2<<<64, 256, 0, stream>>>(ctx_part, qs_part, ctxfT);
    k3_out<<<NROWS / 256, 256, 0, stream>>>(Q, ctxfT, out);
}